// Round 14
// baseline (41.149 us; speedup 1.0000x reference)
//
#include <hip/hip_runtime.h>

#define N_NODES 50000
#define N_EDGES 800000
#define FEAT    128

#define NRANGE  8
#define NSLICE  32
#define NBLK    (NRANGE * NSLICE)      // 256 blocks, 1/CU
#define RN      (N_NODES / NRANGE)     // 6250 nodes per range
#define RNP     6400                   // padded stride (25.6 KB f32 LDS bins)
#define SLICE_Q (N_EDGES / NSLICE / 4) // 6250 quads per slice
#define TB      1024

// ws layout: partial[NBLK][RNP] bf16(ushort) | li0[N_NODES] f32 | sum f32 | ticket u32

__device__ __forceinline__ float bf2f(unsigned short h) {
    return __uint_as_float(((unsigned)h) << 16);
}
__device__ __forceinline__ unsigned short f2bf(float f) {
    return (unsigned short)((__float_as_uint(f) + 0x8000u) >> 16);
}

__global__ void pack_init(const float* __restrict__ li,
                          float* __restrict__ li0,
                          float* sum, unsigned* ticket) {
    int i = blockIdx.x * blockDim.x + threadIdx.x;
    if (i < N_NODES) li0[i] = li[(size_t)i * FEAT];   // pack feature column 0
    if (i == 0) { *sum = 0.0f; *ticket = 0u; }
}

// accum: block (r,s) streams slice s, gathers packed li0 (L2-resident),
// filters rows to range r, LDS-atomic accumulates, flushes bf16 partial.
// Siblings of a slice (same s, 8 ranges) share bid%8 == s%8 -> same XCD.
__global__ __launch_bounds__(TB) void range_accum(
        const float* __restrict__ li0,
        const float* __restrict__ w,
        const int* __restrict__ row,
        const int* __restrict__ col,
        unsigned short* __restrict__ partial) {
    __shared__ float accl[RNP];                    // 25.6 KB
    const int s  = blockIdx.x & (NSLICE - 1);
    const int r  = blockIdx.x >> 5;
    const int lo = r * RN;

    float4* az = (float4*)accl;
    for (int i = threadIdx.x; i < RNP / 4; i += TB)
        az[i] = make_float4(0.f, 0.f, 0.f, 0.f);
    __syncthreads();

    const float4* wq = (const float4*)w   + (size_t)s * SLICE_Q;
    const int4*   rq = (const int4*)row   + (size_t)s * SLICE_Q;
    const int4*   cq = (const int4*)col   + (size_t)s * SLICE_Q;

    for (int q = threadIdx.x; q < SLICE_Q; q += TB) {
        float4 wv = wq[q];
        int4   rv = rq[q];
        int4   cv = cq[q];
        // unconditional gathers (col always in-bounds; issue immediately)
        float g0 = li0[cv.x];
        float g1 = li0[cv.y];
        float g2 = li0[cv.z];
        float g3 = li0[cv.w];
        int a;
        a = rv.x - lo; if ((unsigned)a < RN) atomicAdd(&accl[a], wv.x * g0);
        a = rv.y - lo; if ((unsigned)a < RN) atomicAdd(&accl[a], wv.y * g1);
        a = rv.z - lo; if ((unsigned)a < RN) atomicAdd(&accl[a], wv.z * g2);
        a = rv.w - lo; if ((unsigned)a < RN) atomicAdd(&accl[a], wv.w * g3);
    }
    __syncthreads();

    // flush as bf16: halves partial write traffic (and reduce's read)
    ushort4* pdst = (ushort4*)(partial + (size_t)blockIdx.x * RNP);
    for (int i = threadIdx.x; i < RNP / 4; i += TB) {
        float4 v = az[i];
        ushort4 h;
        h.x = f2bf(v.x); h.y = f2bf(v.y); h.z = f2bf(v.z); h.w = f2bf(v.w);
        pdst[i] = h;
    }
}

// reduce: one node/thread, sum 32 bf16 slice-partials, relu, block-reduce,
// ticket-gated sigmoid finalize.
__global__ void reduce_fin(const unsigned short* __restrict__ partial,
                           float* __restrict__ sum,
                           unsigned* __restrict__ ticket,
                           float* __restrict__ out) {
    int n = blockIdx.x * blockDim.x + threadIdx.x;
    float local = 0.0f;
    if (n < N_NODES) {
        int rr = n / RN;
        int nl = n - rr * RN;
        const unsigned short* base = partial + (size_t)(rr * NSLICE) * RNP + nl;
        float a0 = 0.f, a1 = 0.f, a2 = 0.f, a3 = 0.f;
        #pragma unroll
        for (int b = 0; b < NSLICE; b += 4) {
            a0 += bf2f(base[(size_t)(b + 0) * RNP]);
            a1 += bf2f(base[(size_t)(b + 1) * RNP]);
            a2 += bf2f(base[(size_t)(b + 2) * RNP]);
            a3 += bf2f(base[(size_t)(b + 3) * RNP]);
        }
        local = fmaxf(a0 + a1 + a2 + a3, 0.f);
    }
    #pragma unroll
    for (int off = 32; off > 0; off >>= 1)
        local += __shfl_down(local, off, 64);
    __shared__ float sm[4];
    if ((threadIdx.x & 63) == 0) sm[threadIdx.x >> 6] = local;
    __syncthreads();
    if (threadIdx.x == 0) {
        atomicAdd(sum, sm[0] + sm[1] + sm[2] + sm[3]);
        __threadfence();
        unsigned old = atomicAdd(ticket, 1u);
        if (old == gridDim.x - 1) {
            float v = __hip_atomic_load(sum, __ATOMIC_RELAXED, __HIP_MEMORY_SCOPE_AGENT);
            out[0] = 1.0f / (1.0f + expf(-v));
        }
    }
}

// ---------------- fallback (tiny ws): global atomics ----------------

__global__ void zero_acc(float* __restrict__ acc, float* sum, unsigned* ticket) {
    int i = blockIdx.x * blockDim.x + threadIdx.x;
    if (i < N_NODES) acc[i] = 0.0f;
    if (i == 0) { *sum = 0.0f; *ticket = 0u; }
}

__global__ void edge_scatter4(const float* __restrict__ li,
                              const float* __restrict__ w,
                              const int* __restrict__ row,
                              const int* __restrict__ col,
                              float* __restrict__ acc) {
    int t = blockIdx.x * blockDim.x + threadIdx.x;
    if (t < N_EDGES / 4) {
        float4 wv = ((const float4*)w)[t];
        int4   rv = ((const int4*)row)[t];
        int4   cv = ((const int4*)col)[t];
        atomicAdd(&acc[rv.x], wv.x * li[(size_t)cv.x * FEAT]);
        atomicAdd(&acc[rv.y], wv.y * li[(size_t)cv.y * FEAT]);
        atomicAdd(&acc[rv.z], wv.z * li[(size_t)cv.z * FEAT]);
        atomicAdd(&acc[rv.w], wv.w * li[(size_t)cv.w * FEAT]);
    }
}

__global__ void relu_sum_fin(const float* __restrict__ acc,
                             float* __restrict__ sum,
                             unsigned* __restrict__ ticket,
                             float* __restrict__ out) {
    float local = 0.0f;
    for (int i = blockIdx.x * blockDim.x + threadIdx.x; i < N_NODES / 4;
         i += gridDim.x * blockDim.x) {
        float4 a = ((const float4*)acc)[i];
        local += fmaxf(a.x, 0.f) + fmaxf(a.y, 0.f) +
                 fmaxf(a.z, 0.f) + fmaxf(a.w, 0.f);
    }
    #pragma unroll
    for (int off = 32; off > 0; off >>= 1)
        local += __shfl_down(local, off, 64);
    __shared__ float sm[4];
    if ((threadIdx.x & 63) == 0) sm[threadIdx.x >> 6] = local;
    __syncthreads();
    if (threadIdx.x == 0) {
        atomicAdd(sum, sm[0] + sm[1] + sm[2] + sm[3]);
        __threadfence();
        unsigned old = atomicAdd(ticket, 1u);
        if (old == gridDim.x - 1) {
            float v = __hip_atomic_load(sum, __ATOMIC_RELAXED, __HIP_MEMORY_SCOPE_AGENT);
            out[0] = 1.0f / (1.0f + expf(-v));
        }
    }
}

extern "C" void kernel_launch(void* const* d_in, const int* in_sizes, int n_in,
                              void* d_out, int out_size, void* d_ws, size_t ws_size,
                              hipStream_t stream) {
    const float* li  = (const float*)d_in[0];
    const float* w   = (const float*)d_in[1];
    const int*   row = (const int*)d_in[2];
    const int*   col = (const int*)d_in[3];
    float* out = (float*)d_out;

    size_t need = (size_t)NBLK * RNP * 2 + (size_t)N_NODES * 4 + 16;

    if (ws_size >= need) {
        unsigned short* partial = (unsigned short*)d_ws;
        float*          li0     = (float*)(partial + (size_t)NBLK * RNP);
        float*          sum     = li0 + N_NODES;
        unsigned*       ticket  = (unsigned*)(sum + 1);

        pack_init<<<(N_NODES + 255) / 256, 256, 0, stream>>>(li, li0, sum, ticket);
        range_accum<<<NBLK, TB, 0, stream>>>(li0, w, row, col, partial);
        reduce_fin<<<(N_NODES + 255) / 256, 256, 0, stream>>>(partial, sum, ticket, out);
    } else {
        float*    acc    = (float*)d_ws;
        float*    sum    = acc + N_NODES;
        unsigned* ticket = (unsigned*)(sum + 1);

        zero_acc<<<(N_NODES + 255) / 256, 256, 0, stream>>>(acc, sum, ticket);
        edge_scatter4<<<(N_EDGES / 4 + 255) / 256, 256, 0, stream>>>(li, w, row, col, acc);
        relu_sum_fin<<<49, 256, 0, stream>>>(acc, sum, ticket, out);
    }
}